// Round 23
// baseline (101.541 us; speedup 1.0000x reference)
//
#include <hip/hip_runtime.h>
#include <math.h>

// B=2, T=2048, D=768, H=12, HD=64
typedef __attribute__((ext_vector_type(8))) __bf16 bf16x8;
typedef __attribute__((ext_vector_type(4))) __bf16 bf16x4;
typedef __attribute__((ext_vector_type(4))) float f32x4;

#define GLOAD_LDS16(gsrc, ldst) \
  __builtin_amdgcn_global_load_lds((__attribute__((address_space(1))) const void*)(gsrc), \
                                   (__attribute__((address_space(3))) void*)(ldst), 16, 0, 0)

__device__ __forceinline__ float fexp2(float x) {
#if __has_builtin(__builtin_amdgcn_exp2f)
  return __builtin_amdgcn_exp2f(x);
#else
  return exp2f(x);
#endif
}

// Fused conversion kernel (R18-validated): one launch, three preps.
//  bid <  3072          : x fp32 -> bf16 flat (float4 per thread)
//  3072 <= bid < 4800   : w_qkv^T 32x32 tile transpose-convert (768x2304)
//  bid >= 4800          : w_out^T 32x32 tile transpose-convert (768x768)
__global__ __launch_bounds__(256)
void cvt_fused_kernel(const float* __restrict__ x, __bf16* __restrict__ xb,
                      const float* __restrict__ wqkv, __bf16* __restrict__ wqkvT,
                      const float* __restrict__ wout, __bf16* __restrict__ woT) {
  __shared__ float t[32][33];
  const int bid = blockIdx.x;
  if (bid < 3072) {
    int i = bid * 256 + threadIdx.x;
    float4 f = ((const float4*)x)[i];
    bf16x4 o;
    o[0] = (__bf16)f.x; o[1] = (__bf16)f.y; o[2] = (__bf16)f.z; o[3] = (__bf16)f.w;
    ((bf16x4*)xb)[i] = o;
    return;
  }
  const float* in;
  __bf16* out;
  int R, C, bx, by;
  if (bid < 4800) {
    int tt = bid - 3072;
    bx = tt % 72; by = tt / 72;
    in = wqkv; out = wqkvT; R = 768; C = 2304;
  } else {
    int tt = bid - 4800;
    bx = tt % 24; by = tt / 24;
    in = wout; out = woT; R = 768; C = 768;
  }
  int c0 = bx * 32, r0 = by * 32;
  int tc = threadIdx.x & 31, tr = threadIdx.x >> 5;
#pragma unroll
  for (int i = 0; i < 4; ++i)
    t[tr + 8 * i][tc] = in[(size_t)(r0 + tr + 8 * i) * C + c0 + tc];
  __syncthreads();
#pragma unroll
  for (int i = 0; i < 4; ++i)
    out[(size_t)(c0 + tr + 8 * i) * R + r0 + tc] = (__bf16)t[tc][tr + 8 * i];
}

// TN GEMM: C[M][N] = A[M][K] * B[N][K]^T (+bias). BMxBN tile, BK=64, WAVES waves.
// BUFS=3: counted-vmcnt distance-2 pipeline (R14-validated). BUFS=2: simple dbuf.
template<int EPI, int BM, int BN, int WAVES, int WGM, int WGN, int BUFS>
__global__ __launch_bounds__(WAVES * 64, 3)
void gemm_tn_kernel(const __bf16* __restrict__ A, const __bf16* __restrict__ Bm,
                    const float* __restrict__ bias, float* __restrict__ outF,
                    __bf16* __restrict__ qo, __bf16* __restrict__ ko, __bf16* __restrict__ vo,
                    int M, int N, int K, int NBX, int NNX, int PPX) {
  constexpr int NTA = BM / 16, NTB = BN / 16;
  constexpr int NA = 2 * NTA;               // A segments (2 k-halves)
  constexpr int NSEG = 2 * NTA + 2 * NTB;   // 1KB segments per K-step
  constexpr int LPTH = (NSEG + WAVES - 1) / WAVES;
  constexpr int LPTR = NSEG % WAVES;        // waves < LPTR stage LPTH, rest LPTH-1
  constexpr int LLO = (LPTR == 0) ? LPTH : LPTH - 1;
  constexpr int AM = NTA / WGM;
  constexpr int BNF = NTB / WGN;
  const int lane = threadIdx.x & 63;
  const int wave = threadIdx.x >> 6;
  const int r16 = lane & 15, g = lane >> 4;
  const int id = blockIdx.x;
  const int xcd = id & 7, slot = id >> 3;
  const int nxn = NBX / NNX;
  const int mg = xcd / nxn, ng = xcd % nxn;
  const int lp = slot / NNX, ln = slot - (slot / NNX) * NNX;
  const int mBase = (mg * PPX + lp) * BM, nBase = (ng * NNX + ln) * BN;
  __shared__ __align__(16) __bf16 lds[BUFS][NSEG * 512];

  f32x4 acc[AM][BNF];
#pragma unroll
  for (int i = 0; i < AM; ++i)
#pragma unroll
    for (int j = 0; j < BNF; ++j) acc[i][j] = (f32x4){0.f, 0.f, 0.f, 0.f};

  const int mw = (wave / WGN) * AM;
  const int nw = (wave % WGN) * BNF;

  auto stage = [&](int ke, int b) {
#pragma unroll
    for (int i = 0; i < LPTH; ++i) {
      int s = wave + i * WAVES;             // interleaved; guard is wave-uniform
      if (LPTR == 0 || s < NSEG) {
        int isB = (s >= NA);
        int sb = isB ? s - NA : s;
        int nt = isB ? NTB : NTA;
        int ks = sb / nt, t8 = sb - ks * nt;
        int row = (isB ? nBase : mBase) + t8 * 16 + r16;
        const __bf16* src = (isB ? Bm : A) + (size_t)row * K + ke + ks * 32 + g * 8;
        GLOAD_LDS16(src, &lds[b][s * 512]);
      }
    }
  };

  auto mfma_step = [&](const __bf16* L) {
#pragma unroll
    for (int ks = 0; ks < 2; ++ks) {
      bf16x8 af[AM], bfr[BNF];
#pragma unroll
      for (int i = 0; i < AM; ++i)
        af[i] = *(const bf16x8*)&L[((ks * NTA + mw + i) * 64 + lane) * 8];
#pragma unroll
      for (int j = 0; j < BNF; ++j)
        bfr[j] = *(const bf16x8*)&L[((NA + ks * NTB + nw + j) * 64 + lane) * 8];
      __builtin_amdgcn_s_setprio(1);
#pragma unroll
      for (int i = 0; i < AM; ++i)
#pragma unroll
        for (int j = 0; j < BNF; ++j)
          acc[i][j] = __builtin_amdgcn_mfma_f32_16x16x32_bf16(af[i], bfr[j], acc[i][j], 0, 0, 0);
      __builtin_amdgcn_s_setprio(0);
    }
  };

  const int nt = K >> 6;
  if constexpr (BUFS == 2) {
    stage(0, 0);
    int cur = 0;
    for (int t = 0; t < nt; ++t) {
      __syncthreads();
      if (t + 1 < nt) stage((t + 1) << 6, cur ^ 1);
      mfma_step(lds[cur]);
      cur ^= 1;
    }
  } else {
    stage(0, 0);
    stage(64, 1);
    int cur = 0;
    for (int t = 0; t < nt; ++t) {
      if (t + 1 < nt) {
        if (LPTR != 0 && wave < LPTR) asm volatile("s_waitcnt vmcnt(%0)" :: "i"(LPTH) : "memory");
        else                          asm volatile("s_waitcnt vmcnt(%0)" :: "i"(LLO) : "memory");
      } else {
        asm volatile("s_waitcnt vmcnt(0)" ::: "memory");
      }
      __builtin_amdgcn_sched_barrier(0);
      __builtin_amdgcn_s_barrier();
      __builtin_amdgcn_sched_barrier(0);
      int nxt = cur + 2; if (nxt >= 3) nxt -= 3;
      if (t + 2 < nt) stage((t + 2) << 6, nxt);
      mfma_step(lds[cur]);
      if (++cur == 3) cur = 0;
    }
  }

#pragma unroll
  for (int i = 0; i < AM; ++i) {
#pragma unroll
    for (int j = 0; j < BNF; ++j) {
      int c = nBase + (nw + j) * 16 + r16;
      float bb = bias[c];
#pragma unroll
      for (int e = 0; e < 4; ++e) {
        int r = mBase + (mw + i) * 16 + g * 4 + e;
        float val = acc[i][j][e] + bb;
        if (EPI == 0) {
          int which = c / 768;             // 0:q 1:k 2:v
          int cc = c - which * 768;
          int hh = cc >> 6, dd = cc & 63;
          int bI = r >> 11, tt = r & 2047;
          if (which == 0) {
            // fold 1/sqrt(64) * log2(e) into q (softmax runs in exp2 space)
            qo[(((size_t)(bI * 12 + hh)) * 2048 + tt) * 64 + dd] = (__bf16)(val * 0.180336880f);
          } else if (which == 1) {
            ko[(((size_t)(bI * 12 + hh)) * 2048 + tt) * 64 + dd] = (__bf16)val;
          } else {
            vo[(((size_t)(bI * 12 + hh)) * 64 + dd) * 2048 + tt] = (__bf16)val;  // V^T [B,H,64,T]
          }
        } else {
          outF[(size_t)r * N + c] = val;
        }
      }
    }
  }
}

// Flash attention, causal, swapped-QK^T, O^T accumulation, causal-paired tiles,
// strip-split 4-wave blocks. R12-EXACT (best measured attn variant):
// 768 uniform blocks (3/CU), wave w owns ONE 16-row q-strip (waves 0,1 = tile p
// [Kt=Kp], waves 2,3 = tile a [Kt=Ka<Kp]); untracked softmax in exp2 space.
__global__ __launch_bounds__(256, 2)
void attn_kernel(const __bf16* __restrict__ qg, const __bf16* __restrict__ kg,
                 const __bf16* __restrict__ vtg, __bf16* __restrict__ yatt) {
  const int id = blockIdx.x;
  const int chunk = id & 7, within = id >> 3;   // XCD chunk = 3 heads (L2-resident K/V)
  const int bh = chunk * 3 + (within >> 5);
  const int a = within & 31, p = 63 - a;        // paired 32-row q-tiles
  const int Ka = (a >> 1) + 1, Kp = (p >> 1) + 1;   // Kp > Ka always
  const int lane = threadIdx.x & 63, wave = threadIdx.x >> 6;  // wave 0..3
  const int r16 = lane & 15, g = lane >> 4;
  const int bI = bh / 12, h = bh - bI * 12;
  const size_t headoff = (size_t)bh * 2048 * 64;
  const __bf16* Q = qg + headoff;
  const __bf16* Kh = kg + headoff;
  const __bf16* VT = vtg + headoff;             // [64][2048]

  __shared__ __align__(16) __bf16 Kbuf[2][4096];   // [64 k-rows][8 chunks] swizzled
  __shared__ __align__(16) __bf16 Vbuf[2][4096];   // [64 d-rows][8 chunks] swizzled
  __shared__ __align__(16) __bf16 Plds[4][16][72]; // per-wave strip

  const int myTile = (wave < 2) ? p : a;
  const int myKt   = (wave < 2) ? Kp : Ka;
  const int rowQ   = myTile * 32 + (wave & 1) * 16 + r16;

  bf16x8 qf[2];
#pragma unroll
  for (int ks = 0; ks < 2; ++ks)
    qf[ks] = *(const bf16x8*)&Q[(size_t)rowQ * 64 + ks * 32 + g * 8];

  int srow[2], scl[2];
#pragma unroll
  for (int i = 0; i < 2; ++i) {
    int c = (i * 4 + wave) * 64 + lane;
    srow[i] = c >> 3;
    scl[i] = (c & 7) ^ (srow[i] & 7);
  }
  auto stage = [&](int kt, int b) {
#pragma unroll
    for (int i = 0; i < 2; ++i) {
      GLOAD_LDS16(&Kh[(size_t)(kt * 64 + srow[i]) * 64 + scl[i] * 8], &Kbuf[b][(i * 4 + wave) * 512]);
      GLOAD_LDS16(&VT[(size_t)srow[i] * 2048 + kt * 64 + scl[i] * 8], &Vbuf[b][(i * 4 + wave) * 512]);
    }
  };

  f32x4 o[4];
#pragma unroll
  for (int j = 0; j < 4; ++j) o[j] = (f32x4){0.f, 0.f, 0.f, 0.f};
  float l = 0.f;

  stage(0, 0);
  for (int kt = 0; kt < Kp; ++kt) {
    const int cur = kt & 1;
    __syncthreads();
    if (kt + 1 < Kp) stage(kt + 1, cur ^ 1);
    if (kt < myKt) {
      f32x4 st[4];
#pragma unroll
      for (int j = 0; j < 4; ++j) st[j] = (f32x4){0.f, 0.f, 0.f, 0.f};
      __builtin_amdgcn_s_setprio(1);
#pragma unroll
      for (int ks = 0; ks < 2; ++ks)
#pragma unroll
        for (int j = 0; j < 4; ++j) {
          int row = j * 16 + r16;
          int cp = (ks * 4 + g) ^ (row & 7);
          bf16x8 kf = *(const bf16x8*)&Kbuf[cur][(row * 8 + cp) * 8];
          st[j] = __builtin_amdgcn_mfma_f32_16x16x32_bf16(kf, qf[ks], st[j], 0, 0, 0);
        }
      __builtin_amdgcn_s_setprio(0);
      bf16x8 vf[2][4];
#pragma unroll
      for (int ks = 0; ks < 2; ++ks)
#pragma unroll
        for (int dj = 0; dj < 4; ++dj) {
          int row = dj * 16 + r16;
          int cp = (ks * 4 + g) ^ (row & 7);
          vf[ks][dj] = *(const bf16x8*)&Vbuf[cur][(row * 8 + cp) * 8];
        }
      if (kt == myKt - 1) {
#pragma unroll
        for (int j = 0; j < 4; ++j)
#pragma unroll
          for (int e = 0; e < 4; ++e)
            if (kt * 64 + j * 16 + 4 * g + e > rowQ) st[j][e] = -INFINITY;
      }
      float ls = 0.f;
#pragma unroll
      for (int j = 0; j < 4; ++j)
#pragma unroll
        for (int e = 0; e < 4; ++e) {
          float pv = fexp2(st[j][e]);
          st[j][e] = pv;
          ls += pv;
        }
      ls += __shfl_xor(ls, 16, 64);
      ls += __shfl_xor(ls, 32, 64);
      l += ls;
#pragma unroll
      for (int j = 0; j < 4; ++j) {
        bf16x4 pk;
#pragma unroll
        for (int e = 0; e < 4; ++e) pk[e] = (__bf16)st[j][e];
        *(bf16x4*)&Plds[wave][r16][j * 16 + 4 * g] = pk;
      }
      __builtin_amdgcn_s_setprio(1);
#pragma unroll
      for (int ks = 0; ks < 2; ++ks) {
        bf16x8 pf = *(const bf16x8*)&Plds[wave][r16][ks * 32 + g * 8];
#pragma unroll
        for (int dj = 0; dj < 4; ++dj)
          o[dj] = __builtin_amdgcn_mfma_f32_16x16x32_bf16(vf[ks][dj], pf, o[dj], 0, 0, 0);
      }
      __builtin_amdgcn_s_setprio(0);
    }
  }

  float inv = 1.0f / l;
#pragma unroll
  for (int dj = 0; dj < 4; ++dj) {
    bf16x4 ov;
#pragma unroll
    for (int e = 0; e < 4; ++e) ov[e] = (__bf16)(o[dj][e] * inv);
    *(bf16x4*)&yatt[((size_t)(bI * 2048 + rowQ)) * 768 + h * 64 + dj * 16 + 4 * g] = ov;
  }
}

extern "C" void kernel_launch(void* const* d_in, const int* in_sizes, int n_in,
                              void* d_out, int out_size, void* d_ws, size_t ws_size,
                              hipStream_t stream) {
  (void)in_sizes; (void)n_in; (void)out_size; (void)ws_size;
  const float* x     = (const float*)d_in[0];
  const float* w_qkv = (const float*)d_in[1];
  const float* b_qkv = (const float*)d_in[2];
  const float* w_out = (const float*)d_in[3];
  const float* b_out = (const float*)d_in[4];
  float* out = (float*)d_out;

  char* ws = (char*)d_ws;
  __bf16* xb    = (__bf16*)(ws);              // [4096][768]
  __bf16* wqkvT = (__bf16*)(ws + 6291456);    // [2304][768]
  __bf16* woT   = (__bf16*)(ws + 9830400);    // [768][768]
  __bf16* qb    = (__bf16*)(ws + 11010048);   // [B,H,T,64]  (pre-scaled by 0.125*log2e)
  __bf16* kb    = (__bf16*)(ws + 17301504);   // [B,H,T,64]
  __bf16* vtb   = (__bf16*)(ws + 23592960);   // [B,H,64,T]  (V transposed)
  __bf16* yatt  = (__bf16*)(ws + 29884416);   // [4096][768]

  // one fused conversion launch (x -> bf16; w_qkv^T; w_out^T)
  cvt_fused_kernel<<<5376, 256, 0, stream>>>(x, xb, w_qkv, wqkvT, w_out, woT);
  // QKV: R14 config (best measured 41.9us): 128x288, 12 waves, 3-buf counted,
  // 256 blocks = exactly 1/CU; each XCD owns one 288-col B-slice (L2-resident).
  gemm_tn_kernel<0, 128, 288, 12, 2, 6, 3><<<256, 768, 0, stream>>>(
      xb, wqkvT, b_qkv, nullptr, qb, kb, vtb, 4096, 2304, 768, 8, 1, 32);
  // attn: R12-exact strip-split, 768 uniform blocks (3/CU)
  attn_kernel<<<768, 256, 0, stream>>>(qb, kb, vtb, yatt);
  // out-proj: 64x96 tiles, 512 blocks (2/CU), 3-buf counted; XCD rect 16x4
  gemm_tn_kernel<1, 64, 96, 4, 2, 2, 3><<<512, 256, 0, stream>>>(
      yatt, woT, b_out, out, nullptr, nullptr, nullptr, 4096, 768, 768, 8, 4, 16);
}

// Round 24
// 100.603 us; speedup vs baseline: 1.0093x; 1.0093x over previous
//
#include <hip/hip_runtime.h>
#include <math.h>

// B=2, T=2048, D=768, H=12, HD=64
typedef __attribute__((ext_vector_type(8))) __bf16 bf16x8;
typedef __attribute__((ext_vector_type(4))) __bf16 bf16x4;
typedef __attribute__((ext_vector_type(4))) float f32x4;

#define GLOAD_LDS16(gsrc, ldst) \
  __builtin_amdgcn_global_load_lds((__attribute__((address_space(1))) const void*)(gsrc), \
                                   (__attribute__((address_space(3))) void*)(ldst), 16, 0, 0)

__device__ __forceinline__ float fexp2(float x) {
#if __has_builtin(__builtin_amdgcn_exp2f)
  return __builtin_amdgcn_exp2f(x);
#else
  return exp2f(x);
#endif
}

// Fused conversion kernel (R18-validated): one launch, three preps.
//  bid <  3072          : x fp32 -> bf16 flat (float4 per thread)
//  3072 <= bid < 4800   : w_qkv^T 32x32 tile transpose-convert (768x2304)
//  bid >= 4800          : w_out^T 32x32 tile transpose-convert (768x768)
__global__ __launch_bounds__(256)
void cvt_fused_kernel(const float* __restrict__ x, __bf16* __restrict__ xb,
                      const float* __restrict__ wqkv, __bf16* __restrict__ wqkvT,
                      const float* __restrict__ wout, __bf16* __restrict__ woT) {
  __shared__ float t[32][33];
  const int bid = blockIdx.x;
  if (bid < 3072) {
    int i = bid * 256 + threadIdx.x;
    float4 f = ((const float4*)x)[i];
    bf16x4 o;
    o[0] = (__bf16)f.x; o[1] = (__bf16)f.y; o[2] = (__bf16)f.z; o[3] = (__bf16)f.w;
    ((bf16x4*)xb)[i] = o;
    return;
  }
  const float* in;
  __bf16* out;
  int R, C, bx, by;
  if (bid < 4800) {
    int tt = bid - 3072;
    bx = tt % 72; by = tt / 72;
    in = wqkv; out = wqkvT; R = 768; C = 2304;
  } else {
    int tt = bid - 4800;
    bx = tt % 24; by = tt / 24;
    in = wout; out = woT; R = 768; C = 768;
  }
  int c0 = bx * 32, r0 = by * 32;
  int tc = threadIdx.x & 31, tr = threadIdx.x >> 5;
#pragma unroll
  for (int i = 0; i < 4; ++i)
    t[tr + 8 * i][tc] = in[(size_t)(r0 + tr + 8 * i) * C + c0 + tc];
  __syncthreads();
#pragma unroll
  for (int i = 0; i < 4; ++i)
    out[(size_t)(c0 + tr + 8 * i) * R + r0 + tc] = (__bf16)t[tc][tr + 8 * i];
}

// TN GEMM: C[M][N] = A[M][K] * B[N][K]^T (+bias). BMxBN tile, BK=64, WAVES waves.
// BUFS=3: counted-vmcnt distance-2 pipeline (R14-validated). BUFS=2: simple dbuf.
template<int EPI, int BM, int BN, int WAVES, int WGM, int WGN, int BUFS>
__global__ __launch_bounds__(WAVES * 64, 3)
void gemm_tn_kernel(const __bf16* __restrict__ A, const __bf16* __restrict__ Bm,
                    const float* __restrict__ bias, float* __restrict__ outF,
                    __bf16* __restrict__ qo, __bf16* __restrict__ ko, __bf16* __restrict__ vo,
                    int M, int N, int K, int NBX, int NNX, int PPX) {
  constexpr int NTA = BM / 16, NTB = BN / 16;
  constexpr int NA = 2 * NTA;               // A segments (2 k-halves)
  constexpr int NSEG = 2 * NTA + 2 * NTB;   // 1KB segments per K-step
  constexpr int LPTH = (NSEG + WAVES - 1) / WAVES;
  constexpr int LPTR = NSEG % WAVES;        // waves < LPTR stage LPTH, rest LPTH-1
  constexpr int LLO = (LPTR == 0) ? LPTH : LPTH - 1;
  constexpr int AM = NTA / WGM;
  constexpr int BNF = NTB / WGN;
  const int lane = threadIdx.x & 63;
  const int wave = threadIdx.x >> 6;
  const int r16 = lane & 15, g = lane >> 4;
  const int id = blockIdx.x;
  const int xcd = id & 7, slot = id >> 3;
  const int nxn = NBX / NNX;
  const int mg = xcd / nxn, ng = xcd % nxn;
  const int lp = slot / NNX, ln = slot - (slot / NNX) * NNX;
  const int mBase = (mg * PPX + lp) * BM, nBase = (ng * NNX + ln) * BN;
  __shared__ __align__(16) __bf16 lds[BUFS][NSEG * 512];

  f32x4 acc[AM][BNF];
#pragma unroll
  for (int i = 0; i < AM; ++i)
#pragma unroll
    for (int j = 0; j < BNF; ++j) acc[i][j] = (f32x4){0.f, 0.f, 0.f, 0.f};

  const int mw = (wave / WGN) * AM;
  const int nw = (wave % WGN) * BNF;

  auto stage = [&](int ke, int b) {
#pragma unroll
    for (int i = 0; i < LPTH; ++i) {
      int s = wave + i * WAVES;             // interleaved; guard is wave-uniform
      if (LPTR == 0 || s < NSEG) {
        int isB = (s >= NA);
        int sb = isB ? s - NA : s;
        int nt = isB ? NTB : NTA;
        int ks = sb / nt, t8 = sb - ks * nt;
        int row = (isB ? nBase : mBase) + t8 * 16 + r16;
        const __bf16* src = (isB ? Bm : A) + (size_t)row * K + ke + ks * 32 + g * 8;
        GLOAD_LDS16(src, &lds[b][s * 512]);
      }
    }
  };

  auto mfma_step = [&](const __bf16* L) {
#pragma unroll
    for (int ks = 0; ks < 2; ++ks) {
      bf16x8 af[AM], bfr[BNF];
#pragma unroll
      for (int i = 0; i < AM; ++i)
        af[i] = *(const bf16x8*)&L[((ks * NTA + mw + i) * 64 + lane) * 8];
#pragma unroll
      for (int j = 0; j < BNF; ++j)
        bfr[j] = *(const bf16x8*)&L[((NA + ks * NTB + nw + j) * 64 + lane) * 8];
      __builtin_amdgcn_s_setprio(1);
#pragma unroll
      for (int i = 0; i < AM; ++i)
#pragma unroll
        for (int j = 0; j < BNF; ++j)
          acc[i][j] = __builtin_amdgcn_mfma_f32_16x16x32_bf16(af[i], bfr[j], acc[i][j], 0, 0, 0);
      __builtin_amdgcn_s_setprio(0);
    }
  };

  const int nt = K >> 6;
  if constexpr (BUFS == 2) {
    stage(0, 0);
    int cur = 0;
    for (int t = 0; t < nt; ++t) {
      __syncthreads();
      if (t + 1 < nt) stage((t + 1) << 6, cur ^ 1);
      mfma_step(lds[cur]);
      cur ^= 1;
    }
  } else {
    stage(0, 0);
    stage(64, 1);
    int cur = 0;
    for (int t = 0; t < nt; ++t) {
      if (t + 1 < nt) {
        if (LPTR != 0 && wave < LPTR) asm volatile("s_waitcnt vmcnt(%0)" :: "i"(LPTH) : "memory");
        else                          asm volatile("s_waitcnt vmcnt(%0)" :: "i"(LLO) : "memory");
      } else {
        asm volatile("s_waitcnt vmcnt(0)" ::: "memory");
      }
      __builtin_amdgcn_sched_barrier(0);
      __builtin_amdgcn_s_barrier();
      __builtin_amdgcn_sched_barrier(0);
      int nxt = cur + 2; if (nxt >= 3) nxt -= 3;
      if (t + 2 < nt) stage((t + 2) << 6, nxt);
      mfma_step(lds[cur]);
      if (++cur == 3) cur = 0;
    }
  }

#pragma unroll
  for (int i = 0; i < AM; ++i) {
#pragma unroll
    for (int j = 0; j < BNF; ++j) {
      int c = nBase + (nw + j) * 16 + r16;
      float bb = bias[c];
#pragma unroll
      for (int e = 0; e < 4; ++e) {
        int r = mBase + (mw + i) * 16 + g * 4 + e;
        float val = acc[i][j][e] + bb;
        if (EPI == 0) {
          int which = c / 768;             // 0:q 1:k 2:v
          int cc = c - which * 768;
          int hh = cc >> 6, dd = cc & 63;
          int bI = r >> 11, tt = r & 2047;
          if (which == 0) {
            // fold 1/sqrt(64) * log2(e) into q (softmax runs in exp2 space)
            qo[(((size_t)(bI * 12 + hh)) * 2048 + tt) * 64 + dd] = (__bf16)(val * 0.180336880f);
          } else if (which == 1) {
            ko[(((size_t)(bI * 12 + hh)) * 2048 + tt) * 64 + dd] = (__bf16)val;
          } else {
            vo[(((size_t)(bI * 12 + hh)) * 64 + dd) * 2048 + tt] = (__bf16)val;  // V^T [B,H,64,T]
          }
        } else {
          outF[(size_t)r * N + c] = val;
        }
      }
    }
  }
}

// Flash attention, causal, swapped-QK^T, O^T accumulation, causal-paired tiles,
// strip-split 4-wave blocks. R12-EXACT (best measured attn variant):
// 768 uniform blocks (3/CU), wave w owns ONE 16-row q-strip (waves 0,1 = tile p
// [Kt=Kp], waves 2,3 = tile a [Kt=Ka<Kp]); untracked softmax in exp2 space.
__global__ __launch_bounds__(256, 2)
void attn_kernel(const __bf16* __restrict__ qg, const __bf16* __restrict__ kg,
                 const __bf16* __restrict__ vtg, __bf16* __restrict__ yatt) {
  const int id = blockIdx.x;
  const int chunk = id & 7, within = id >> 3;   // XCD chunk = 3 heads (L2-resident K/V)
  const int bh = chunk * 3 + (within >> 5);
  const int a = within & 31, p = 63 - a;        // paired 32-row q-tiles
  const int Ka = (a >> 1) + 1, Kp = (p >> 1) + 1;   // Kp > Ka always
  const int lane = threadIdx.x & 63, wave = threadIdx.x >> 6;  // wave 0..3
  const int r16 = lane & 15, g = lane >> 4;
  const int bI = bh / 12, h = bh - bI * 12;
  const size_t headoff = (size_t)bh * 2048 * 64;
  const __bf16* Q = qg + headoff;
  const __bf16* Kh = kg + headoff;
  const __bf16* VT = vtg + headoff;             // [64][2048]

  __shared__ __align__(16) __bf16 Kbuf[2][4096];   // [64 k-rows][8 chunks] swizzled
  __shared__ __align__(16) __bf16 Vbuf[2][4096];   // [64 d-rows][8 chunks] swizzled
  __shared__ __align__(16) __bf16 Plds[4][16][72]; // per-wave strip

  const int myTile = (wave < 2) ? p : a;
  const int myKt   = (wave < 2) ? Kp : Ka;
  const int rowQ   = myTile * 32 + (wave & 1) * 16 + r16;

  bf16x8 qf[2];
#pragma unroll
  for (int ks = 0; ks < 2; ++ks)
    qf[ks] = *(const bf16x8*)&Q[(size_t)rowQ * 64 + ks * 32 + g * 8];

  int srow[2], scl[2];
#pragma unroll
  for (int i = 0; i < 2; ++i) {
    int c = (i * 4 + wave) * 64 + lane;
    srow[i] = c >> 3;
    scl[i] = (c & 7) ^ (srow[i] & 7);
  }
  auto stage = [&](int kt, int b) {
#pragma unroll
    for (int i = 0; i < 2; ++i) {
      GLOAD_LDS16(&Kh[(size_t)(kt * 64 + srow[i]) * 64 + scl[i] * 8], &Kbuf[b][(i * 4 + wave) * 512]);
      GLOAD_LDS16(&VT[(size_t)srow[i] * 2048 + kt * 64 + scl[i] * 8], &Vbuf[b][(i * 4 + wave) * 512]);
    }
  };

  f32x4 o[4];
#pragma unroll
  for (int j = 0; j < 4; ++j) o[j] = (f32x4){0.f, 0.f, 0.f, 0.f};
  float l = 0.f;

  stage(0, 0);
  for (int kt = 0; kt < Kp; ++kt) {
    const int cur = kt & 1;
    __syncthreads();
    if (kt + 1 < Kp) stage(kt + 1, cur ^ 1);
    if (kt < myKt) {
      f32x4 st[4];
#pragma unroll
      for (int j = 0; j < 4; ++j) st[j] = (f32x4){0.f, 0.f, 0.f, 0.f};
      __builtin_amdgcn_s_setprio(1);
#pragma unroll
      for (int ks = 0; ks < 2; ++ks)
#pragma unroll
        for (int j = 0; j < 4; ++j) {
          int row = j * 16 + r16;
          int cp = (ks * 4 + g) ^ (row & 7);
          bf16x8 kf = *(const bf16x8*)&Kbuf[cur][(row * 8 + cp) * 8];
          st[j] = __builtin_amdgcn_mfma_f32_16x16x32_bf16(kf, qf[ks], st[j], 0, 0, 0);
        }
      __builtin_amdgcn_s_setprio(0);
      bf16x8 vf[2][4];
#pragma unroll
      for (int ks = 0; ks < 2; ++ks)
#pragma unroll
        for (int dj = 0; dj < 4; ++dj) {
          int row = dj * 16 + r16;
          int cp = (ks * 4 + g) ^ (row & 7);
          vf[ks][dj] = *(const bf16x8*)&Vbuf[cur][(row * 8 + cp) * 8];
        }
      if (kt == myKt - 1) {
#pragma unroll
        for (int j = 0; j < 4; ++j)
#pragma unroll
          for (int e = 0; e < 4; ++e)
            if (kt * 64 + j * 16 + 4 * g + e > rowQ) st[j][e] = -INFINITY;
      }
      float ls = 0.f;
#pragma unroll
      for (int j = 0; j < 4; ++j)
#pragma unroll
        for (int e = 0; e < 4; ++e) {
          float pv = fexp2(st[j][e]);
          st[j][e] = pv;
          ls += pv;
        }
      ls += __shfl_xor(ls, 16, 64);
      ls += __shfl_xor(ls, 32, 64);
      l += ls;
#pragma unroll
      for (int j = 0; j < 4; ++j) {
        bf16x4 pk;
#pragma unroll
        for (int e = 0; e < 4; ++e) pk[e] = (__bf16)st[j][e];
        *(bf16x4*)&Plds[wave][r16][j * 16 + 4 * g] = pk;
      }
      __builtin_amdgcn_s_setprio(1);
#pragma unroll
      for (int ks = 0; ks < 2; ++ks) {
        bf16x8 pf = *(const bf16x8*)&Plds[wave][r16][ks * 32 + g * 8];
#pragma unroll
        for (int dj = 0; dj < 4; ++dj)
          o[dj] = __builtin_amdgcn_mfma_f32_16x16x32_bf16(vf[ks][dj], pf, o[dj], 0, 0, 0);
      }
      __builtin_amdgcn_s_setprio(0);
    }
  }

  float inv = 1.0f / l;
#pragma unroll
  for (int dj = 0; dj < 4; ++dj) {
    bf16x4 ov;
#pragma unroll
    for (int e = 0; e < 4; ++e) ov[e] = (__bf16)(o[dj][e] * inv);
    *(bf16x4*)&yatt[((size_t)(bI * 2048 + rowQ)) * 768 + h * 64 + dj * 16 + 4 * g] = ov;
  }
}

extern "C" void kernel_launch(void* const* d_in, const int* in_sizes, int n_in,
                              void* d_out, int out_size, void* d_ws, size_t ws_size,
                              hipStream_t stream) {
  (void)in_sizes; (void)n_in; (void)out_size; (void)ws_size;
  const float* x     = (const float*)d_in[0];
  const float* w_qkv = (const float*)d_in[1];
  const float* b_qkv = (const float*)d_in[2];
  const float* w_out = (const float*)d_in[3];
  const float* b_out = (const float*)d_in[4];
  float* out = (float*)d_out;

  char* ws = (char*)d_ws;
  __bf16* xb    = (__bf16*)(ws);              // [4096][768]
  __bf16* wqkvT = (__bf16*)(ws + 6291456);    // [2304][768]
  __bf16* woT   = (__bf16*)(ws + 9830400);    // [768][768]
  __bf16* qb    = (__bf16*)(ws + 11010048);   // [B,H,T,64]  (pre-scaled by 0.125*log2e)
  __bf16* kb    = (__bf16*)(ws + 17301504);   // [B,H,T,64]
  __bf16* vtb   = (__bf16*)(ws + 23592960);   // [B,H,64,T]  (V transposed)
  __bf16* yatt  = (__bf16*)(ws + 29884416);   // [4096][768]

  // one fused conversion launch (x -> bf16; w_qkv^T; w_out^T)
  cvt_fused_kernel<<<5376, 256, 0, stream>>>(x, xb, w_qkv, wqkvT, w_out, woT);
  // QKV: R14 config (best measured 41.9us): 128x288, 12 waves, 3-buf counted,
  // 256 blocks = exactly 1/CU; each XCD owns one 288-col B-slice (L2-resident).
  gemm_tn_kernel<0, 128, 288, 12, 2, 6, 3><<<256, 768, 0, stream>>>(
      xb, wqkvT, b_qkv, nullptr, qb, kb, vtb, 4096, 2304, 768, 8, 1, 32);
  // attn: R12-exact strip-split, 768 uniform blocks (3/CU)
  attn_kernel<<<768, 256, 0, stream>>>(qb, kb, vtb, yatt);
  // out-proj: 64x96 tiles, 512 blocks (2/CU), 3-buf counted; XCD rect 16x4
  gemm_tn_kernel<1, 64, 96, 4, 2, 2, 3><<<512, 256, 0, stream>>>(
      yatt, woT, b_out, out, nullptr, nullptr, nullptr, 4096, 768, 768, 8, 4, 16);
}